// Round 14
// baseline (266.726 us; speedup 1.0000x reference)
//
#include <hip/hip_runtime.h>
#include <math.h>

#define HDIM 128
#define RDIM 20
#define TE 64
#define PT 72            // transposed plane stride in shorts (144 B rows)

typedef __attribute__((ext_vector_type(8))) short short8;
typedef __attribute__((ext_vector_type(4))) short s16x4;
typedef __attribute__((ext_vector_type(4))) float f32x4;

__device__ __forceinline__ float silu_f(float v) { return v / (1.0f + __expf(-v)); }

__device__ __forceinline__ short f2b(float x) {
    unsigned u = __float_as_uint(x);
    u += 0x7fffu + ((u >> 16) & 1u);
    return (short)(u >> 16);
}
__device__ __forceinline__ float b2f(short s) {
    return __uint_as_float(((unsigned)(unsigned short)s) << 16);
}
__device__ __forceinline__ unsigned cvt_pk_bf16(float a, float b) {
    unsigned r;
    asm("v_cvt_pk_bf16_f32 %0, %1, %2" : "=v"(r) : "v"(a), "v"(b));
    return r;
}

// ---------------------------------------------------------------------------
// Packed-weight segment offsets (bf16 elements)
// B-frag: lane l supplies B[k = kb*32 + (l>>4)*8 + j][col = ct*16 + (l&15)].
// ---------------------------------------------------------------------------
#define OFF_PW1   0
#define OFF_PW2   4096
#define OFF_PWI1  53248
#define OFF_PWI2  102400
#define OFF_PWV   249856
#define OFF_PWS1  282624
#define OFF_PWS2  380928
#define PK_TOTAL  528384

// prep: pack weights + convert mu to bf16 (8-wide) + degree histogram +
//       zero messages (float4-wide)
__global__ void prep_kernel(const float* __restrict__ Wf1, const float* __restrict__ Wf2,
                            const float* __restrict__ Wi1, const float* __restrict__ Wi2,
                            const float* __restrict__ Wv,  const float* __restrict__ Ws1,
                            const float* __restrict__ Ws2, short* __restrict__ pk,
                            const float* __restrict__ mu, short* __restrict__ mu_b,
                            const int* __restrict__ ei, int* __restrict__ deg_i,
                            float* __restrict__ msg_zero, int N, int E)
{
    int t = blockIdx.x * 256 + threadIdx.x;
    if (t < PK_TOTAL) {
        const float* W; int Nc; int u; bool pad20 = false;
        if      (t < OFF_PW2)  { W = Wf1; Nc = 128; u = t;            pad20 = true; }
        else if (t < OFF_PWI1) { W = Wf2; Nc = 384; u = t - OFF_PW2;  }
        else if (t < OFF_PWI2) { W = Wi1; Nc = 384; u = t - OFF_PWI1; }
        else if (t < OFF_PWV)  { W = Wi2; Nc = 384; u = t - OFF_PWI2; }
        else if (t < OFF_PWS1) { W = Wv;  Nc = 256; u = t - OFF_PWV;  }
        else if (t < OFF_PWS2) { W = Ws1; Nc = 384; u = t - OFF_PWS1; }
        else                   { W = Ws2; Nc = 384; u = t - OFF_PWS2; }
        int j = u & 7, lane = (u >> 3) & 63, rest = u >> 9;
        int nct = Nc >> 4, ct = rest % nct, kb = rest / nct;
        int k = kb * 32 + ((lane >> 4) << 3) + j;
        int col = ct * 16 + (lane & 15);
        float v = (pad20 && k >= RDIM) ? 0.f : W[(size_t)k * Nc + col];
        pk[t] = f2b(v);
        return;
    }
    int u = t - PK_TOTAL;
    int MU8 = N * 48;                       // N*384/8 eight-wide tasks
    if (u < MU8) {
        const f32x4* src = (const f32x4*)&mu[(size_t)u * 8];
        f32x4 a = src[0], b = src[1];
        short8 v;
#pragma unroll
        for (int jj = 0; jj < 4; ++jj) { v[jj] = f2b(a[jj]); v[4 + jj] = f2b(b[jj]); }
        *(short8*)&mu_b[(size_t)u * 8] = v;
        return;
    }
    u -= MU8;
    if (u < E) { atomicAdd(&deg_i[ei[u]], 1); return; }
    u -= E;
    if (u < N * 128) {
        f32x4 z = {0.f, 0.f, 0.f, 0.f};
        *(f32x4*)&msg_zero[(size_t)u * 4] = z;
    }
}

// ---------------------------------------------------------------------------
// mlp1 (blocks < MB): xbuf = silu(q@Wi1+bi1)@Wi2+bi2
// scatter (blocks >= MB): counting-sort rank scatter (independent work).
// ---------------------------------------------------------------------------
__global__ __launch_bounds__(256) void mlp1_scatter_kernel(
    const float* __restrict__ q, const short* __restrict__ pwA,
    const float* __restrict__ biasA, const short* __restrict__ pwB,
    const float* __restrict__ biasB, short* __restrict__ out, int M, int MB,
    const int* __restrict__ ei, const int* __restrict__ offs,
    int* __restrict__ counters, int* __restrict__ perm, int E)
{
    __shared__ short As[32 * 32];
    __shared__ short s_hh[32 * 384];
    if ((int)blockIdx.x >= MB) {
        int e = ((int)blockIdx.x - MB) * 256 + threadIdx.x;
        if (e < E) {
            int tg = ei[e];
            int pos = offs[tg] + atomicAdd(&counters[tg], 1);
            perm[pos] = e;
        }
        return;
    }
    const int t = threadIdx.x, w = t >> 6, l = t & 63;
    const int lr = l & 15, lg = l >> 4;
    const int row0 = blockIdx.x * 32;

    f32x4 acc1[2][6];
#pragma unroll
    for (int rt = 0; rt < 2; ++rt)
#pragma unroll
        for (int j = 0; j < 6; ++j) acc1[rt][j] = (f32x4){0.f, 0.f, 0.f, 0.f};

    for (int kb = 0; kb < 4; ++kb) {
        if (t < 128) {
            int i = t >> 2, ch = t & 3;
            int row = row0 + i;
            short8 v = {0, 0, 0, 0, 0, 0, 0, 0};
            if (row < M) {
                const float* qp = &q[(size_t)row * 128 + kb * 32 + ch * 8];
                f32x4 f0 = *(const f32x4*)&qp[0];
                f32x4 f1 = *(const f32x4*)&qp[4];
#pragma unroll
                for (int jj = 0; jj < 4; ++jj) { v[jj] = f2b(f0[jj]); v[4 + jj] = f2b(f1[jj]); }
            }
            *(short8*)&As[i * 32 + ((ch ^ (i & 3)) * 8)] = v;
        }
        __syncthreads();
        short8 a[2];
#pragma unroll
        for (int rt = 0; rt < 2; ++rt) {
            int row = rt * 16 + lr;
            a[rt] = *(const short8*)&As[row * 32 + ((lg ^ (row & 3)) * 8)];
        }
#pragma unroll
        for (int j = 0; j < 6; ++j) {
            int ct = w * 6 + j;
            short8 B = *(const short8*)&pwA[((size_t)(kb * 24 + ct) * 64 + l) * 8];
#pragma unroll
            for (int rt = 0; rt < 2; ++rt)
                acc1[rt][j] = __builtin_amdgcn_mfma_f32_16x16x32_bf16(a[rt], B, acc1[rt][j], 0, 0, 0);
        }
        __syncthreads();
    }
#pragma unroll
    for (int j = 0; j < 6; ++j) {
        int colL = (w * 6 + j) * 16 + lr;
        float bv = biasA[colL];
        int cb = colL >> 3, pos = colL & 7;
#pragma unroll
        for (int rt = 0; rt < 2; ++rt)
#pragma unroll
            for (int reg = 0; reg < 4; ++reg) {
                int rowg = rt * 16 + lg * 4 + reg;
                s_hh[rowg * 384 + ((cb ^ (rowg & 7)) * 8) + pos] = f2b(silu_f(acc1[rt][j][reg] + bv));
            }
    }
    __syncthreads();

    f32x4 acc2[2][6];
#pragma unroll
    for (int rt = 0; rt < 2; ++rt)
#pragma unroll
        for (int j = 0; j < 6; ++j) acc2[rt][j] = (f32x4){0.f, 0.f, 0.f, 0.f};
#pragma unroll
    for (int kb2 = 0; kb2 < 12; ++kb2) {
        short8 a2[2];
#pragma unroll
        for (int rt = 0; rt < 2; ++rt) {
            int row = rt * 16 + lr;
            a2[rt] = *(const short8*)&s_hh[row * 384 + (((kb2 * 4 + lg) ^ (row & 7)) * 8)];
        }
#pragma unroll
        for (int j = 0; j < 6; ++j) {
            int ct = w * 6 + j;
            short8 B = *(const short8*)&pwB[((size_t)(kb2 * 24 + ct) * 64 + l) * 8];
#pragma unroll
            for (int rt = 0; rt < 2; ++rt)
                acc2[rt][j] = __builtin_amdgcn_mfma_f32_16x16x32_bf16(a2[rt], B, acc2[rt][j], 0, 0, 0);
        }
    }
#pragma unroll
    for (int j = 0; j < 6; ++j) {
        int colL = (w * 6 + j) * 16 + lr;
        float bv = biasB[colL];
#pragma unroll
        for (int rt = 0; rt < 2; ++rt)
#pragma unroll
            for (int reg = 0; reg < 4; ++reg) {
                int rr = row0 + rt * 16 + lg * 4 + reg;
                if (rr < M) out[(size_t)rr * 384 + colL] = f2b(acc2[rt][j][reg] + bv);
            }
    }
}

// ---------------------------------------------------------------------------
// mix: Wv GEMM (mu_cat in LDS, outmu -> d_out) + si-build (outq -> d_out)
//      + scalar MLP + final update.  Block = 32 nodes (96 mu rows).
// ---------------------------------------------------------------------------
__global__ __launch_bounds__(256) void mix_kernel(
    const float* __restrict__ mu, const float* __restrict__ vector_msg,
    const float* __restrict__ q, const float* __restrict__ scalar_msg,
    const int* __restrict__ deg_i, const short* __restrict__ pwv,
    const short* __restrict__ pwA, const float* __restrict__ biasA,
    const short* __restrict__ pwB, const float* __restrict__ biasB,
    float* __restrict__ outq, float* __restrict__ outmu, int N)
{
    __shared__ short s_mc[96 * 256];   // mu_cat bf16 (48 KB)
    __shared__ short s_hh[32 * 384];   // h / delta (24 KB)
    __shared__ short As[32 * 32];
    __shared__ float s_invn[32];
    const int t = threadIdx.x, w = t >> 6, l = t & 63;
    const int lr = l & 15, lg = l >> 4;
    const int n0 = blockIdx.x * 32;
    const int M3 = 3 * N;

    if (t < 32) {
        int n = n0 + t;
        s_invn[t] = (n < N) ? 1.f / fmaxf((float)deg_i[n], 1.f) : 1.f;
    }
    __syncthreads();

    // ---- phase W: mu_cat = (mu + vec/deg) @ Wv ; outmu written f32 ----
    for (int g = 0; g < 3; ++g) {
        f32x4 acc[2][4];
#pragma unroll
        for (int rt = 0; rt < 2; ++rt)
#pragma unroll
            for (int j = 0; j < 4; ++j) acc[rt][j] = (f32x4){0.f, 0.f, 0.f, 0.f};
        for (int kb = 0; kb < 4; ++kb) {
            if (t < 128) {
                int i = t >> 2, ch = t & 3;
                int lrow = g * 32 + i;
                int r = n0 * 3 + lrow;
                short8 sv = {0, 0, 0, 0, 0, 0, 0, 0};
                if (r < M3) {
                    const float* mp = &mu[(size_t)r * 128 + kb * 32 + ch * 8];
                    const float* vp = &vector_msg[(size_t)r * 128 + kb * 32 + ch * 8];
                    f32x4 m0 = *(const f32x4*)&mp[0], m1 = *(const f32x4*)&mp[4];
                    f32x4 g0 = *(const f32x4*)&vp[0], g1 = *(const f32x4*)&vp[4];
                    float inv = s_invn[lrow / 3];
                    f32x4 v0, v1;
#pragma unroll
                    for (int jj = 0; jj < 4; ++jj) {
                        v0[jj] = fmaf(g0[jj], inv, m0[jj]);
                        v1[jj] = fmaf(g1[jj], inv, m1[jj]);
                        sv[jj] = f2b(v0[jj]); sv[4 + jj] = f2b(v1[jj]);
                    }
                    float* op = &outmu[(size_t)r * 128 + kb * 32 + ch * 8];
                    *(f32x4*)&op[0] = v0;
                    *(f32x4*)&op[4] = v1;
                }
                *(short8*)&As[i * 32 + ((ch ^ (i & 3)) * 8)] = sv;
            }
            __syncthreads();
            short8 a[2];
#pragma unroll
            for (int rt = 0; rt < 2; ++rt) {
                int row = rt * 16 + lr;
                a[rt] = *(const short8*)&As[row * 32 + ((lg ^ (row & 3)) * 8)];
            }
#pragma unroll
            for (int j = 0; j < 4; ++j) {
                int ct = w * 4 + j;
                short8 B = *(const short8*)&pwv[((size_t)(kb * 16 + ct) * 64 + l) * 8];
#pragma unroll
                for (int rt = 0; rt < 2; ++rt)
                    acc[rt][j] = __builtin_amdgcn_mfma_f32_16x16x32_bf16(a[rt], B, acc[rt][j], 0, 0, 0);
            }
            __syncthreads();
        }
#pragma unroll
        for (int j = 0; j < 4; ++j) {
            int colL = (w * 4 + j) * 16 + lr;
#pragma unroll
            for (int rt = 0; rt < 2; ++rt)
#pragma unroll
                for (int reg = 0; reg < 4; ++reg) {
                    int lrow = g * 32 + rt * 16 + lg * 4 + reg;
                    s_mc[lrow * 256 + colL] = f2b(acc[rt][j][reg]);
                }
        }
    }
    __syncthreads();

    // ---- phase A: si = [q + msg/deg -> outq, ||mu_v||] ; layer 1 ----
    f32x4 acc1[2][6];
#pragma unroll
    for (int rt = 0; rt < 2; ++rt)
#pragma unroll
        for (int j = 0; j < 6; ++j) acc1[rt][j] = (f32x4){0.f, 0.f, 0.f, 0.f};

    for (int kb = 0; kb < 8; ++kb) {
        if (t < 128) {
            int i = t >> 2, ch = t & 3;
            int row = n0 + i;
            short8 v = {0, 0, 0, 0, 0, 0, 0, 0};
            if (row < N) {
                if (kb < 4) {
                    int k0 = kb * 32 + ch * 8;
                    const float* qp = &q[(size_t)row * 128 + k0];
                    const float* sp = &scalar_msg[(size_t)row * 128 + k0];
                    f32x4 q0 = *(const f32x4*)&qp[0], q1 = *(const f32x4*)&qp[4];
                    f32x4 s0 = *(const f32x4*)&sp[0], s1 = *(const f32x4*)&sp[4];
                    float inv = s_invn[i];
                    f32x4 o0, o1;
#pragma unroll
                    for (int jj = 0; jj < 4; ++jj) {
                        o0[jj] = fmaf(s0[jj], inv, q0[jj]);
                        o1[jj] = fmaf(s1[jj], inv, q1[jj]);
                        v[jj] = f2b(o0[jj]); v[4 + jj] = f2b(o1[jj]);
                    }
                    float* op = &outq[(size_t)row * 128 + k0];
                    *(f32x4*)&op[0] = o0;
                    *(f32x4*)&op[4] = o1;
                } else {
                    int k0 = (kb - 4) * 32 + ch * 8;
                    const short* b = &s_mc[(i * 3) * 256 + k0];
                    short8 m0 = *(const short8*)&b[0];
                    short8 m1 = *(const short8*)&b[256];
                    short8 m2 = *(const short8*)&b[512];
#pragma unroll
                    for (int jj = 0; jj < 8; ++jj) {
                        float a0 = b2f(m0[jj]), a1 = b2f(m1[jj]), a2 = b2f(m2[jj]);
                        v[jj] = f2b(sqrtf(fmaf(a0, a0, fmaf(a1, a1, fmaf(a2, a2, 1e-8f)))));
                    }
                }
            }
            *(short8*)&As[i * 32 + ((ch ^ (i & 3)) * 8)] = v;
        }
        __syncthreads();
        short8 a[2];
#pragma unroll
        for (int rt = 0; rt < 2; ++rt) {
            int row = rt * 16 + lr;
            a[rt] = *(const short8*)&As[row * 32 + ((lg ^ (row & 3)) * 8)];
        }
#pragma unroll
        for (int j = 0; j < 6; ++j) {
            int ct = w * 6 + j;
            short8 B = *(const short8*)&pwA[((size_t)(kb * 24 + ct) * 64 + l) * 8];
#pragma unroll
            for (int rt = 0; rt < 2; ++rt)
                acc1[rt][j] = __builtin_amdgcn_mfma_f32_16x16x32_bf16(a[rt], B, acc1[rt][j], 0, 0, 0);
        }
        __syncthreads();
    }
#pragma unroll
    for (int j = 0; j < 6; ++j) {
        int colL = (w * 6 + j) * 16 + lr;
        float bv = biasA[colL];
        int cb = colL >> 3, pos = colL & 7;
#pragma unroll
        for (int rt = 0; rt < 2; ++rt)
#pragma unroll
            for (int reg = 0; reg < 4; ++reg) {
                int rowg = rt * 16 + lg * 4 + reg;
                s_hh[rowg * 384 + ((cb ^ (rowg & 7)) * 8) + pos] = f2b(silu_f(acc1[rt][j][reg] + bv));
            }
    }
    __syncthreads();

    // ---- phase B: layer 2 ----
    f32x4 acc2[2][6];
#pragma unroll
    for (int rt = 0; rt < 2; ++rt)
#pragma unroll
        for (int j = 0; j < 6; ++j) acc2[rt][j] = (f32x4){0.f, 0.f, 0.f, 0.f};
#pragma unroll
    for (int kb2 = 0; kb2 < 12; ++kb2) {
        short8 a2[2];
#pragma unroll
        for (int rt = 0; rt < 2; ++rt) {
            int row = rt * 16 + lr;
            a2[rt] = *(const short8*)&s_hh[row * 384 + (((kb2 * 4 + lg) ^ (row & 7)) * 8)];
        }
#pragma unroll
        for (int j = 0; j < 6; ++j) {
            int ct = w * 6 + j;
            short8 B = *(const short8*)&pwB[((size_t)(kb2 * 24 + ct) * 64 + l) * 8];
#pragma unroll
            for (int rt = 0; rt < 2; ++rt)
                acc2[rt][j] = __builtin_amdgcn_mfma_f32_16x16x32_bf16(a2[rt], B, acc2[rt][j], 0, 0, 0);
        }
    }
    __syncthreads();

    // delta (bf16) -> s_hh, row-major [32][384]
#pragma unroll
    for (int j = 0; j < 6; ++j) {
        int colL = (w * 6 + j) * 16 + lr;
        float bv = biasB[colL];
#pragma unroll
        for (int rt = 0; rt < 2; ++rt)
#pragma unroll
            for (int reg = 0; reg < 4; ++reg) {
                int rowg = rt * 16 + lg * 4 + reg;
                s_hh[rowg * 384 + colL] = f2b(acc2[rt][j][reg] + bv);
            }
    }
    __syncthreads();

    // ---- final: outq += dq + dqmu*inner ; outmu += mu_w * dmu_scale ----
    {
        int nl = t >> 3;
        int k0 = (t & 7) * 16;
        int n = n0 + nl;
        if (n < N) {
#pragma unroll
            for (int half = 0; half < 2; ++half) {
                int k = k0 + half * 8;
                short8 dq8 = *(const short8*)&s_hh[nl * 384 + k];
                short8 ds8 = *(const short8*)&s_hh[nl * 384 + 128 + k];
                short8 dm8 = *(const short8*)&s_hh[nl * 384 + 256 + k];
                float inner[8] = {0.f, 0.f, 0.f, 0.f, 0.f, 0.f, 0.f, 0.f};
                float mwv[3][8];
#pragma unroll
                for (int c = 0; c < 3; ++c) {
                    const short* mc = &s_mc[(nl * 3 + c) * 256 + k];
                    short8 v8 = *(const short8*)&mc[0];
                    short8 w8 = *(const short8*)&mc[128];
#pragma unroll
                    for (int jj = 0; jj < 8; ++jj) {
                        float mw = b2f(w8[jj]);
                        inner[jj] = fmaf(b2f(v8[jj]), mw, inner[jj]);
                        mwv[c][jj] = mw;
                    }
                }
                float* qp2 = &outq[(size_t)n * 128 + k];
                f32x4 u0 = *(const f32x4*)&qp2[0];
                f32x4 u1 = *(const f32x4*)&qp2[4];
#pragma unroll
                for (int jj = 0; jj < 4; ++jj) {
                    u0[jj] += b2f(dq8[jj]) + b2f(dm8[jj]) * inner[jj];
                    u1[jj] += b2f(dq8[4 + jj]) + b2f(dm8[4 + jj]) * inner[4 + jj];
                }
                *(f32x4*)&qp2[0] = u0;
                *(f32x4*)&qp2[4] = u1;
#pragma unroll
                for (int c = 0; c < 3; ++c) {
                    float* mp = &outmu[((size_t)n * 3 + c) * 128 + k];
                    f32x4 a0 = *(const f32x4*)&mp[0];
                    f32x4 a1 = *(const f32x4*)&mp[4];
#pragma unroll
                    for (int jj = 0; jj < 4; ++jj) {
                        a0[jj] = fmaf(mwv[c][jj], b2f(ds8[jj]), a0[jj]);
                        a1[jj] = fmaf(mwv[c][4 + jj], b2f(ds8[4 + jj]), a1[jj]);
                    }
                    *(f32x4*)&mp[0] = a0;
                    *(f32x4*)&mp[4] = a1;
                }
            }
        }
    }
}

// ---------------------------------------------------------------------------
// Counting sort prefix scan (histogram lives in prep)
// ---------------------------------------------------------------------------
__global__ __launch_bounds__(1024) void scan_kernel(const int* __restrict__ deg_i,
                                                    int* __restrict__ offs, int N) {
    __shared__ int s[1024];
    int t = threadIdx.x;
    int chunk = (N + 1023) / 1024;
    int a = t * chunk, b = min(a + chunk, N);
    int sum = 0;
    for (int i = a; i < b; ++i) sum += deg_i[i];
    s[t] = sum;
    __syncthreads();
    for (int d = 1; d < 1024; d <<= 1) {
        int v = (t >= d) ? s[t - d] : 0;
        __syncthreads();
        s[t] += v;
        __syncthreads();
    }
    int run = (t > 0) ? s[t - 1] : 0;
    for (int i = a; i < b; ++i) { offs[i] = run; run += deg_i[i]; }
}

// ---------------------------------------------------------------------------
// Segmented scan of the TRANSPOSED bf16 plane [col][row] down sorted targets.
// ---------------------------------------------------------------------------
__device__ __forceinline__ void scan_T(const short* __restrict__ s_pt,
                                       const int* __restrict__ s_tgt,
                                       unsigned bm32, float* __restrict__ dst,
                                       int rowstride, int coloff, int t)
{
    int col = t & 127;
    int r0 = (t >> 7) * 32;
    const short* cp = &s_pt[col * PT + r0];
    float acc = 0.f;
    bool first = (bm32 & 1u) ? false : true;
#pragma unroll
    for (int g = 0; g < 4; ++g) {
        short8 v = *(const short8*)&cp[g * 8];
#pragma unroll
        for (int kk = 0; kk < 8; ++kk) {
            const int k = g * 8 + kk;
            if (k > 0 && ((bm32 >> k) & 1u)) {
                int tg = s_tgt[r0 + k - 1];
                if (tg >= 0) {
                    float* d = dst + (size_t)tg * rowstride + coloff + col;
                    if (first) atomicAdd(d, acc); else *d = acc;
                }
                acc = 0.f; first = false;
            }
            acc += b2f(v[kk]);
        }
    }
    int tg = s_tgt[r0 + 31];
    if (tg >= 0) atomicAdd(dst + (size_t)tg * rowstride + coloff + col, acc);
}

// ---------------------------------------------------------------------------
// Fused edge kernel (MFMA) over target-sorted edges; transposed bf16 plane.
// Planes 1+2 merged into one MFMA pass (single A-read, dual accumulators).
// ---------------------------------------------------------------------------
__global__ __launch_bounds__(256, 4) void edge_kernel(
    const int* __restrict__ ei, const int* __restrict__ perm,
    const float* __restrict__ rbf,
    const float* __restrict__ uv, const float* __restrict__ cutv,
    const short* __restrict__ pw1, const short* __restrict__ pw2,
    const float* __restrict__ bf1, const float* __restrict__ bf2,
    const short* __restrict__ x, const short* __restrict__ mu_b,
    float* __restrict__ scalar_msg, float* __restrict__ vector_msg,
    int E)
{
    __shared__ __align__(16) short s_h[64 * 128];
    __shared__ __align__(16) short s_pt[128 * PT];
    __shared__ int   s_eid[TE];
    __shared__ int   s_tgt[TE];
    __shared__ int   s_src[TE];
    __shared__ float s_cut[TE];
    __shared__ float s_uv[TE * 3];

    const int t = threadIdx.x;
    const int w = t >> 6;
    const int l = t & 63;
    const int e0 = blockIdx.x * TE;

    if (t < TE) {
        int p = e0 + t;
        int e = (p < E) ? perm[p] : -1;
        s_eid[t] = e;
        s_tgt[t] = (e >= 0) ? ei[e] : -1;
        s_src[t] = (e >= 0) ? ei[(size_t)E + e] : 0;
        s_cut[t] = (e >= 0) ? cutv[e] : 0.f;
    }
    __syncthreads();
    if (t < TE * 3) {
        int i = t / 3, c = t - i * 3;
        int e = s_eid[i];
        s_uv[t] = (e >= 0) ? uv[(size_t)e * 3 + c] : 0.f;
    }
    bool bp = (l > 0) && (s_tgt[l] != s_tgt[l - 1]);
    unsigned long long bl = __ballot(bp);
    unsigned bmlo = __builtin_amdgcn_readfirstlane((unsigned)bl);
    unsigned bmhi = __builtin_amdgcn_readfirstlane((unsigned)(bl >> 32));

    // ---- MFMA1: h = silu(rbf @ Wf1 + bf1) ----
    short8 Ar;
#pragma unroll
    for (int j = 0; j < 8; ++j) Ar[j] = 0;
    {
        int erow = w * 16 + (l & 15);
        int eidr = s_eid[erow];
        int g = l >> 4;
        if (eidr >= 0) {
            const float* rp = &rbf[(size_t)eidr * RDIM];
            if (g < 2) {
                float4 f0 = *(const float4*)&rp[g * 8];
                float4 f1 = *(const float4*)&rp[g * 8 + 4];
                Ar[0] = f2b(f0.x); Ar[1] = f2b(f0.y); Ar[2] = f2b(f0.z); Ar[3] = f2b(f0.w);
                Ar[4] = f2b(f1.x); Ar[5] = f2b(f1.y); Ar[6] = f2b(f1.z); Ar[7] = f2b(f1.w);
            } else if (g == 2) {
                float4 f0 = *(const float4*)&rp[16];
                Ar[0] = f2b(f0.x); Ar[1] = f2b(f0.y); Ar[2] = f2b(f0.z); Ar[3] = f2b(f0.w);
            }
        }
    }
    {
        f32x4 Hc[8];
#pragma unroll
        for (int ct = 0; ct < 8; ++ct) {
            f32x4 z = {0.f, 0.f, 0.f, 0.f};
            short8 Bw = *(const short8*)&pw1[(ct * 64 + l) * 8];
            Hc[ct] = __builtin_amdgcn_mfma_f32_16x16x32_bf16(Ar, Bw, z, 0, 0, 0);
        }
#pragma unroll
        for (int ct = 0; ct < 8; ++ct) {
            int colbase = ct * 16 + (l & 15);
            float b1 = bf1[colbase];
#pragma unroll
            for (int reg = 0; reg < 4; ++reg) {
                int rowg = w * 16 + ((l >> 4) * 4 + reg);
                float v = silu_f(Hc[ct][reg] + b1);
                s_h[rowg * 128 + (((colbase >> 3) ^ (rowg & 7)) * 8) + (colbase & 7)] = f2b(v);
            }
        }
    }
    __syncthreads();

    const int tj = t & 15, ti = t >> 4;
    const int c0 = tj * 8;
    const int r0d = 4 * ((ti + tj) & 15);

    auto mfma_plane = [&](int p) {
        f32x4 C[4][2];
#pragma unroll
        for (int rt = 0; rt < 4; ++rt)
#pragma unroll
            for (int c2 = 0; c2 < 2; ++c2) C[rt][c2] = (f32x4){0.f, 0.f, 0.f, 0.f};
#pragma unroll
        for (int kb = 0; kb < 4; ++kb) {
            short8 A[4];
#pragma unroll
            for (int rt = 0; rt < 4; ++rt) {
                int row = rt * 16 + (l & 15);
                A[rt] = *(const short8*)&s_h[row * 128 + (((kb * 4 + (l >> 4)) ^ (row & 7)) * 8)];
            }
#pragma unroll
            for (int c2 = 0; c2 < 2; ++c2) {
                int ct = p * 8 + w * 2 + c2;
                short8 B = *(const short8*)&pw2[(((kb * 24 + ct) * 64 + l) * 8)];
#pragma unroll
                for (int rt = 0; rt < 4; ++rt)
                    C[rt][c2] = __builtin_amdgcn_mfma_f32_16x16x32_bf16(A[rt], B, C[rt][c2], 0, 0, 0);
            }
        }
        const int lg = l >> 4;
#pragma unroll
        for (int c2 = 0; c2 < 2; ++c2) {
            int colL = w * 32 + c2 * 16 + (l & 15);
            float bv = bf2[p * 128 + colL];
#pragma unroll
            for (int rt = 0; rt < 4; ++rt) {
                float4 cu4 = *(float4*)&s_cut[rt * 16 + lg * 4];
                float v0 = (C[rt][c2][0] + bv) * cu4.x;
                float v1 = (C[rt][c2][1] + bv) * cu4.y;
                float v2 = (C[rt][c2][2] + bv) * cu4.z;
                float v3 = (C[rt][c2][3] + bv) * cu4.w;
                *(uint2*)&s_pt[colL * PT + rt * 16 + lg * 4] =
                    make_uint2(cvt_pk_bf16(v0, v1), cvt_pk_bf16(v2, v3));
            }
        }
    };

    // plane 0: filter_q -> scalar messages
    mfma_plane(0);
    __syncthreads();
    {
        float xf[4][8];
#pragma unroll
        for (int rr = 0; rr < 4; ++rr) {
            int s = s_src[r0d + rr];
            short8 xv = *(const short8*)&x[(size_t)s * 384 + c0];
#pragma unroll
            for (int c = 0; c < 8; ++c) xf[rr][c] = b2f(xv[c]);
        }
#pragma unroll
        for (int cc = 0; cc < 8; ++cc) {
            short* pp = &s_pt[(c0 + cc) * PT + r0d];
            s16x4 pv = *(s16x4*)pp;
            float o0 = b2f(pv[0]) * xf[0][cc];
            float o1 = b2f(pv[1]) * xf[1][cc];
            float o2 = b2f(pv[2]) * xf[2][cc];
            float o3 = b2f(pv[3]) * xf[3][cc];
            *(uint2*)pp = make_uint2(cvt_pk_bf16(o0, o1), cvt_pk_bf16(o2, o3));
        }
    }
    __syncthreads();
    scan_T(s_pt, s_tgt, (t >> 7) ? bmhi : bmlo, scalar_msg, HDIM, 0, t);
    __syncthreads();

    // ===== merged planes 1+2: single A pass, dual accumulators =====
    f32x4 C12[4][4];
#pragma unroll
    for (int rt = 0; rt < 4; ++rt)
#pragma unroll
        for (int c4 = 0; c4 < 4; ++c4) C12[rt][c4] = (f32x4){0.f, 0.f, 0.f, 0.f};
#pragma unroll
    for (int kb = 0; kb < 4; ++kb) {
        short8 A[4];
#pragma unroll
        for (int rt = 0; rt < 4; ++rt) {
            int row = rt * 16 + (l & 15);
            A[rt] = *(const short8*)&s_h[row * 128 + (((kb * 4 + (l >> 4)) ^ (row & 7)) * 8)];
        }
#pragma unroll
        for (int c4 = 0; c4 < 4; ++c4) {
            int p = 1 + (c4 >> 1);
            int ct = p * 8 + w * 2 + (c4 & 1);
            short8 B = *(const short8*)&pw2[(((kb * 24 + ct) * 64 + l) * 8)];
#pragma unroll
            for (int rt = 0; rt < 4; ++rt)
                C12[rt][c4] = __builtin_amdgcn_mfma_f32_16x16x32_bf16(A[rt], B, C12[rt][c4], 0, 0, 0);
        }
    }
    // epilogue writer for plane p using C12 columns [cbase, cbase+1]
    auto plane_epi = [&](int p, int cbase) {
        const int lg = l >> 4;
#pragma unroll
        for (int c2 = 0; c2 < 2; ++c2) {
            int colL = w * 32 + c2 * 16 + (l & 15);
            float bv = bf2[p * 128 + colL];
#pragma unroll
            for (int rt = 0; rt < 4; ++rt) {
                float4 cu4 = *(float4*)&s_cut[rt * 16 + lg * 4];
                float v0 = (C12[rt][cbase + c2][0] + bv) * cu4.x;
                float v1 = (C12[rt][cbase + c2][1] + bv) * cu4.y;
                float v2 = (C12[rt][cbase + c2][2] + bv) * cu4.z;
                float v3 = (C12[rt][cbase + c2][3] + bv) * cu4.w;
                *(uint2*)&s_pt[colL * PT + rt * 16 + lg * 4] =
                    make_uint2(cvt_pk_bf16(v0, v1), cvt_pk_bf16(v2, v3));
            }
        }
    };

    // plane 1 -> vr
    plane_epi(1, 0);
    __syncthreads();
    float vr[4][8];
    {
        float xf[4][8];
#pragma unroll
        for (int rr = 0; rr < 4; ++rr) {
            int s = s_src[r0d + rr];
            short8 xv = *(const short8*)&x[(size_t)s * 384 + 128 + c0];
#pragma unroll
            for (int c = 0; c < 8; ++c) xf[rr][c] = b2f(xv[c]);
        }
#pragma unroll
        for (int cc = 0; cc < 8; ++cc) {
            s16x4 pv = *(const s16x4*)&s_pt[(c0 + cc) * PT + r0d];
#pragma unroll
            for (int rr = 0; rr < 4; ++rr) vr[rr][cc] = b2f(pv[rr]) * xf[rr][cc];
        }
    }
    __syncthreads();

    // plane 2 -> vm (from held accumulators; no second MFMA pass)
    plane_epi(2, 2);
    __syncthreads();
    float vm[4][8];
    {
        float xf[4][8];
#pragma unroll
        for (int rr = 0; rr < 4; ++rr) {
            int s = s_src[r0d + rr];
            short8 xv = *(const short8*)&x[(size_t)s * 384 + 256 + c0];
#pragma unroll
            for (int c = 0; c < 8; ++c) xf[rr][c] = b2f(xv[c]);
        }
#pragma unroll
        for (int cc = 0; cc < 8; ++cc) {
            s16x4 pv = *(const s16x4*)&s_pt[(c0 + cc) * PT + r0d];
#pragma unroll
            for (int rr = 0; rr < 4; ++rr) vm[rr][cc] = b2f(pv[rr]) * xf[rr][cc];
        }
    }

    // vector components x/y/z: combine + scan
#pragma unroll
    for (int comp = 0; comp < 3; ++comp) {
        if (comp > 0) __syncthreads();
        float uvv[4], mf[4][8];
#pragma unroll
        for (int rr = 0; rr < 4; ++rr) {
            uvv[rr] = s_uv[(r0d + rr) * 3 + comp];
            int s = s_src[r0d + rr];
            short8 mv = *(const short8*)&mu_b[(size_t)s * 384 + comp * 128 + c0];
#pragma unroll
            for (int c = 0; c < 8; ++c) mf[rr][c] = b2f(mv[c]);
        }
#pragma unroll
        for (int cc = 0; cc < 8; ++cc) {
            float o0 = fmaf(uvv[0], vr[0][cc], mf[0][cc] * vm[0][cc]);
            float o1 = fmaf(uvv[1], vr[1][cc], mf[1][cc] * vm[1][cc]);
            float o2 = fmaf(uvv[2], vr[2][cc], mf[2][cc] * vm[2][cc]);
            float o3 = fmaf(uvv[3], vr[3][cc], mf[3][cc] * vm[3][cc]);
            *(uint2*)&s_pt[(c0 + cc) * PT + r0d] =
                make_uint2(cvt_pk_bf16(o0, o1), cvt_pk_bf16(o2, o3));
        }
        __syncthreads();
        scan_T(s_pt, s_tgt, (t >> 7) ? bmhi : bmlo, vector_msg, 384, comp * 128, t);
    }
}

// ---------------------------------------------------------------------------
extern "C" void kernel_launch(void* const* d_in, const int* in_sizes, int n_in,
                              void* d_out, int out_size, void* d_ws, size_t ws_size,
                              hipStream_t stream)
{
    const float* q    = (const float*)d_in[0];
    const float* mu   = (const float*)d_in[1];
    const int*   ei   = (const int*)d_in[2];
    const float* rbf  = (const float*)d_in[3];
    const float* uv   = (const float*)d_in[4];
    const float* cutv = (const float*)d_in[5];
    const float* Wi1  = (const float*)d_in[6];
    const float* bi1  = (const float*)d_in[7];
    const float* Wi2  = (const float*)d_in[8];
    const float* bi2  = (const float*)d_in[9];
    const float* Wf1  = (const float*)d_in[10];
    const float* bf1  = (const float*)d_in[11];
    const float* Wf2  = (const float*)d_in[12];
    const float* bf2  = (const float*)d_in[13];
    const float* Wv   = (const float*)d_in[14];
    const float* Ws1  = (const float*)d_in[15];
    const float* bs1  = (const float*)d_in[16];
    const float* Ws2  = (const float*)d_in[17];
    const float* bs2  = (const float*)d_in[18];

    const int N = in_sizes[0] / HDIM;     // 10000
    const int E = in_sizes[2] / 2;        // 320000

    float* ws = (float*)d_ws;
    float* scalar_msg = ws;
    float* vector_msg = ws + (size_t)N * 128;
    short* xbuf       = (short*)(ws + (size_t)N * 512);
    short* mu_b       = (short*)(ws + (size_t)N * 704);
    int*   ibase      = (int*)(ws + (size_t)N * 896);
    int*   deg_i      = ibase;
    int*   counters   = ibase + N;
    int*   offs       = ibase + 2 * (size_t)N;
    int*   perm       = ibase + 3 * (size_t)N;
    short* pk         = (short*)(perm + E);

    float* outq  = (float*)d_out;
    float* outmu = (float*)d_out + (size_t)N * 128;

    hipMemsetAsync(ibase, 0, (size_t)2 * N * sizeof(int), stream);    // deg + counters

    dim3 blk(256);
    int prep_items = PK_TOTAL + N * 48 + E + N * 128;
    prep_kernel<<<(prep_items + 255) / 256, blk, 0, stream>>>(Wf1, Wf2, Wi1, Wi2, Wv, Ws1, Ws2,
                                                              pk, mu, mu_b, ei, deg_i,
                                                              scalar_msg, N, E);

    scan_kernel<<<1, dim3(1024), 0, stream>>>(deg_i, offs, N);

    int MB = (N + 31) / 32;
    int SB = (E + 255) / 256;
    mlp1_scatter_kernel<<<MB + SB, blk, 0, stream>>>(q, pk + OFF_PWI1, bi1,
                                                     pk + OFF_PWI2, bi2, xbuf, N, MB,
                                                     ei, offs, counters, perm, E);

    edge_kernel<<<(E + TE - 1) / TE, blk, 0, stream>>>(ei, perm, rbf, uv, cutv,
                                                       pk + OFF_PW1, pk + OFF_PW2, bf1, bf2,
                                                       xbuf, mu_b, scalar_msg, vector_msg, E);

    mix_kernel<<<(N + 31) / 32, blk, 0, stream>>>(mu, vector_msg, q, scalar_msg, deg_i,
                                                  pk + OFF_PWV, pk + OFF_PWS1, bs1,
                                                  pk + OFF_PWS2, bs2, outq, outmu, N);
}

// Round 15
// 249.974 us; speedup vs baseline: 1.0670x; 1.0670x over previous
//
#include <hip/hip_runtime.h>
#include <math.h>

#define HDIM 128
#define RDIM 20
#define TE 64
#define PT 72            // transposed plane stride in shorts (144 B rows)

typedef __attribute__((ext_vector_type(8))) short short8;
typedef __attribute__((ext_vector_type(4))) short s16x4;
typedef __attribute__((ext_vector_type(4))) float f32x4;

__device__ __forceinline__ float silu_f(float v) { return v / (1.0f + __expf(-v)); }

__device__ __forceinline__ short f2b(float x) {
    unsigned u = __float_as_uint(x);
    u += 0x7fffu + ((u >> 16) & 1u);
    return (short)(u >> 16);
}
__device__ __forceinline__ float b2f(short s) {
    return __uint_as_float(((unsigned)(unsigned short)s) << 16);
}
__device__ __forceinline__ unsigned cvt_pk_bf16(float a, float b) {
    unsigned r;
    asm("v_cvt_pk_bf16_f32 %0, %1, %2" : "=v"(r) : "v"(a), "v"(b));
    return r;
}

// ---------------------------------------------------------------------------
// Packed-weight segment offsets (bf16 elements)
// B-frag: lane l supplies B[k = kb*32 + (l>>4)*8 + j][col = ct*16 + (l&15)].
// ---------------------------------------------------------------------------
#define OFF_PW1   0
#define OFF_PW2   4096
#define OFF_PWI1  53248
#define OFF_PWI2  102400
#define OFF_PWV   249856
#define OFF_PWS1  282624
#define OFF_PWS2  380928
#define PK_TOTAL  528384

// prep: pack weights + convert mu to bf16 (8-wide) + degree histogram +
//       zero messages (float4-wide)
__global__ void prep_kernel(const float* __restrict__ Wf1, const float* __restrict__ Wf2,
                            const float* __restrict__ Wi1, const float* __restrict__ Wi2,
                            const float* __restrict__ Wv,  const float* __restrict__ Ws1,
                            const float* __restrict__ Ws2, short* __restrict__ pk,
                            const float* __restrict__ mu, short* __restrict__ mu_b,
                            const int* __restrict__ ei, int* __restrict__ deg_i,
                            float* __restrict__ msg_zero, int N, int E)
{
    int t = blockIdx.x * 256 + threadIdx.x;
    if (t < PK_TOTAL) {
        const float* W; int Nc; int u; bool pad20 = false;
        if      (t < OFF_PW2)  { W = Wf1; Nc = 128; u = t;            pad20 = true; }
        else if (t < OFF_PWI1) { W = Wf2; Nc = 384; u = t - OFF_PW2;  }
        else if (t < OFF_PWI2) { W = Wi1; Nc = 384; u = t - OFF_PWI1; }
        else if (t < OFF_PWV)  { W = Wi2; Nc = 384; u = t - OFF_PWI2; }
        else if (t < OFF_PWS1) { W = Wv;  Nc = 256; u = t - OFF_PWV;  }
        else if (t < OFF_PWS2) { W = Ws1; Nc = 384; u = t - OFF_PWS1; }
        else                   { W = Ws2; Nc = 384; u = t - OFF_PWS2; }
        int j = u & 7, lane = (u >> 3) & 63, rest = u >> 9;
        int nct = Nc >> 4, ct = rest % nct, kb = rest / nct;
        int k = kb * 32 + ((lane >> 4) << 3) + j;
        int col = ct * 16 + (lane & 15);
        float v = (pad20 && k >= RDIM) ? 0.f : W[(size_t)k * Nc + col];
        pk[t] = f2b(v);
        return;
    }
    int u = t - PK_TOTAL;
    int MU8 = N * 48;                       // N*384/8 eight-wide tasks
    if (u < MU8) {
        const f32x4* src = (const f32x4*)&mu[(size_t)u * 8];
        f32x4 a = src[0], b = src[1];
        short8 v;
#pragma unroll
        for (int jj = 0; jj < 4; ++jj) { v[jj] = f2b(a[jj]); v[4 + jj] = f2b(b[jj]); }
        *(short8*)&mu_b[(size_t)u * 8] = v;
        return;
    }
    u -= MU8;
    if (u < E) { atomicAdd(&deg_i[ei[u]], 1); return; }
    u -= E;
    if (u < N * 128) {
        f32x4 z = {0.f, 0.f, 0.f, 0.f};
        *(f32x4*)&msg_zero[(size_t)u * 4] = z;
    }
}

// ---------------------------------------------------------------------------
// mlp1 (blocks < MB): xbuf = silu(q@Wi1+bi1)@Wi2+bi2
// scatter (blocks >= MB): counting-sort rank scatter (independent work).
// ---------------------------------------------------------------------------
__global__ __launch_bounds__(256) void mlp1_scatter_kernel(
    const float* __restrict__ q, const short* __restrict__ pwA,
    const float* __restrict__ biasA, const short* __restrict__ pwB,
    const float* __restrict__ biasB, short* __restrict__ out, int M, int MB,
    const int* __restrict__ ei, const int* __restrict__ offs,
    int* __restrict__ counters, int* __restrict__ perm, int E)
{
    __shared__ short As[32 * 32];
    __shared__ short s_hh[32 * 384];
    if ((int)blockIdx.x >= MB) {
        int e = ((int)blockIdx.x - MB) * 256 + threadIdx.x;
        if (e < E) {
            int tg = ei[e];
            int pos = offs[tg] + atomicAdd(&counters[tg], 1);
            perm[pos] = e;
        }
        return;
    }
    const int t = threadIdx.x, w = t >> 6, l = t & 63;
    const int lr = l & 15, lg = l >> 4;
    const int row0 = blockIdx.x * 32;

    f32x4 acc1[2][6];
#pragma unroll
    for (int rt = 0; rt < 2; ++rt)
#pragma unroll
        for (int j = 0; j < 6; ++j) acc1[rt][j] = (f32x4){0.f, 0.f, 0.f, 0.f};

    for (int kb = 0; kb < 4; ++kb) {
        if (t < 128) {
            int i = t >> 2, ch = t & 3;
            int row = row0 + i;
            short8 v = {0, 0, 0, 0, 0, 0, 0, 0};
            if (row < M) {
                const float* qp = &q[(size_t)row * 128 + kb * 32 + ch * 8];
                f32x4 f0 = *(const f32x4*)&qp[0];
                f32x4 f1 = *(const f32x4*)&qp[4];
#pragma unroll
                for (int jj = 0; jj < 4; ++jj) { v[jj] = f2b(f0[jj]); v[4 + jj] = f2b(f1[jj]); }
            }
            *(short8*)&As[i * 32 + ((ch ^ (i & 3)) * 8)] = v;
        }
        __syncthreads();
        short8 a[2];
#pragma unroll
        for (int rt = 0; rt < 2; ++rt) {
            int row = rt * 16 + lr;
            a[rt] = *(const short8*)&As[row * 32 + ((lg ^ (row & 3)) * 8)];
        }
#pragma unroll
        for (int j = 0; j < 6; ++j) {
            int ct = w * 6 + j;
            short8 B = *(const short8*)&pwA[((size_t)(kb * 24 + ct) * 64 + l) * 8];
#pragma unroll
            for (int rt = 0; rt < 2; ++rt)
                acc1[rt][j] = __builtin_amdgcn_mfma_f32_16x16x32_bf16(a[rt], B, acc1[rt][j], 0, 0, 0);
        }
        __syncthreads();
    }
#pragma unroll
    for (int j = 0; j < 6; ++j) {
        int colL = (w * 6 + j) * 16 + lr;
        float bv = biasA[colL];
        int cb = colL >> 3, pos = colL & 7;
#pragma unroll
        for (int rt = 0; rt < 2; ++rt)
#pragma unroll
            for (int reg = 0; reg < 4; ++reg) {
                int rowg = rt * 16 + lg * 4 + reg;
                s_hh[rowg * 384 + ((cb ^ (rowg & 7)) * 8) + pos] = f2b(silu_f(acc1[rt][j][reg] + bv));
            }
    }
    __syncthreads();

    f32x4 acc2[2][6];
#pragma unroll
    for (int rt = 0; rt < 2; ++rt)
#pragma unroll
        for (int j = 0; j < 6; ++j) acc2[rt][j] = (f32x4){0.f, 0.f, 0.f, 0.f};
#pragma unroll
    for (int kb2 = 0; kb2 < 12; ++kb2) {
        short8 a2[2];
#pragma unroll
        for (int rt = 0; rt < 2; ++rt) {
            int row = rt * 16 + lr;
            a2[rt] = *(const short8*)&s_hh[row * 384 + (((kb2 * 4 + lg) ^ (row & 7)) * 8)];
        }
#pragma unroll
        for (int j = 0; j < 6; ++j) {
            int ct = w * 6 + j;
            short8 B = *(const short8*)&pwB[((size_t)(kb2 * 24 + ct) * 64 + l) * 8];
#pragma unroll
            for (int rt = 0; rt < 2; ++rt)
                acc2[rt][j] = __builtin_amdgcn_mfma_f32_16x16x32_bf16(a2[rt], B, acc2[rt][j], 0, 0, 0);
        }
    }
#pragma unroll
    for (int j = 0; j < 6; ++j) {
        int colL = (w * 6 + j) * 16 + lr;
        float bv = biasB[colL];
#pragma unroll
        for (int rt = 0; rt < 2; ++rt)
#pragma unroll
            for (int reg = 0; reg < 4; ++reg) {
                int rr = row0 + rt * 16 + lg * 4 + reg;
                if (rr < M) out[(size_t)rr * 384 + colL] = f2b(acc2[rt][j][reg] + bv);
            }
    }
}

// ---------------------------------------------------------------------------
// mix: Wv GEMM (mu_cat in LDS, outmu -> d_out) + si-build (outq -> d_out)
//      + scalar MLP + final update.  Block = 32 nodes (96 mu rows).
// (3-group phase W, short register lifetimes)
// ---------------------------------------------------------------------------
__global__ __launch_bounds__(256) void mix_kernel(
    const float* __restrict__ mu, const float* __restrict__ vector_msg,
    const float* __restrict__ q, const float* __restrict__ scalar_msg,
    const int* __restrict__ deg_i, const short* __restrict__ pwv,
    const short* __restrict__ pwA, const float* __restrict__ biasA,
    const short* __restrict__ pwB, const float* __restrict__ biasB,
    float* __restrict__ outq, float* __restrict__ outmu, int N)
{
    __shared__ short s_mc[96 * 256];   // mu_cat bf16 (48 KB)
    __shared__ short s_hh[32 * 384];   // h / delta (24 KB)
    __shared__ short As[32 * 32];
    __shared__ float s_invn[32];
    const int t = threadIdx.x, w = t >> 6, l = t & 63;
    const int lr = l & 15, lg = l >> 4;
    const int n0 = blockIdx.x * 32;
    const int M3 = 3 * N;

    if (t < 32) {
        int n = n0 + t;
        s_invn[t] = (n < N) ? 1.f / fmaxf((float)deg_i[n], 1.f) : 1.f;
    }
    __syncthreads();

    // ---- phase W: mu_cat = (mu + vec/deg) @ Wv ; outmu written f32 ----
    for (int g = 0; g < 3; ++g) {
        f32x4 acc[2][4];
#pragma unroll
        for (int rt = 0; rt < 2; ++rt)
#pragma unroll
            for (int j = 0; j < 4; ++j) acc[rt][j] = (f32x4){0.f, 0.f, 0.f, 0.f};
        for (int kb = 0; kb < 4; ++kb) {
            if (t < 128) {
                int i = t >> 2, ch = t & 3;
                int lrow = g * 32 + i;
                int r = n0 * 3 + lrow;
                short8 sv = {0, 0, 0, 0, 0, 0, 0, 0};
                if (r < M3) {
                    const float* mp = &mu[(size_t)r * 128 + kb * 32 + ch * 8];
                    const float* vp = &vector_msg[(size_t)r * 128 + kb * 32 + ch * 8];
                    f32x4 m0 = *(const f32x4*)&mp[0], m1 = *(const f32x4*)&mp[4];
                    f32x4 g0 = *(const f32x4*)&vp[0], g1 = *(const f32x4*)&vp[4];
                    float inv = s_invn[lrow / 3];
                    f32x4 v0, v1;
#pragma unroll
                    for (int jj = 0; jj < 4; ++jj) {
                        v0[jj] = fmaf(g0[jj], inv, m0[jj]);
                        v1[jj] = fmaf(g1[jj], inv, m1[jj]);
                        sv[jj] = f2b(v0[jj]); sv[4 + jj] = f2b(v1[jj]);
                    }
                    float* op = &outmu[(size_t)r * 128 + kb * 32 + ch * 8];
                    *(f32x4*)&op[0] = v0;
                    *(f32x4*)&op[4] = v1;
                }
                *(short8*)&As[i * 32 + ((ch ^ (i & 3)) * 8)] = sv;
            }
            __syncthreads();
            short8 a[2];
#pragma unroll
            for (int rt = 0; rt < 2; ++rt) {
                int row = rt * 16 + lr;
                a[rt] = *(const short8*)&As[row * 32 + ((lg ^ (row & 3)) * 8)];
            }
#pragma unroll
            for (int j = 0; j < 4; ++j) {
                int ct = w * 4 + j;
                short8 B = *(const short8*)&pwv[((size_t)(kb * 16 + ct) * 64 + l) * 8];
#pragma unroll
                for (int rt = 0; rt < 2; ++rt)
                    acc[rt][j] = __builtin_amdgcn_mfma_f32_16x16x32_bf16(a[rt], B, acc[rt][j], 0, 0, 0);
            }
            __syncthreads();
        }
#pragma unroll
        for (int j = 0; j < 4; ++j) {
            int colL = (w * 4 + j) * 16 + lr;
#pragma unroll
            for (int rt = 0; rt < 2; ++rt)
#pragma unroll
                for (int reg = 0; reg < 4; ++reg) {
                    int lrow = g * 32 + rt * 16 + lg * 4 + reg;
                    s_mc[lrow * 256 + colL] = f2b(acc[rt][j][reg]);
                }
        }
    }
    __syncthreads();

    // ---- phase A: si = [q + msg/deg -> outq, ||mu_v||] ; layer 1 ----
    f32x4 acc1[2][6];
#pragma unroll
    for (int rt = 0; rt < 2; ++rt)
#pragma unroll
        for (int j = 0; j < 6; ++j) acc1[rt][j] = (f32x4){0.f, 0.f, 0.f, 0.f};

    for (int kb = 0; kb < 8; ++kb) {
        if (t < 128) {
            int i = t >> 2, ch = t & 3;
            int row = n0 + i;
            short8 v = {0, 0, 0, 0, 0, 0, 0, 0};
            if (row < N) {
                if (kb < 4) {
                    int k0 = kb * 32 + ch * 8;
                    const float* qp = &q[(size_t)row * 128 + k0];
                    const float* sp = &scalar_msg[(size_t)row * 128 + k0];
                    f32x4 q0 = *(const f32x4*)&qp[0], q1 = *(const f32x4*)&qp[4];
                    f32x4 s0 = *(const f32x4*)&sp[0], s1 = *(const f32x4*)&sp[4];
                    float inv = s_invn[i];
                    f32x4 o0, o1;
#pragma unroll
                    for (int jj = 0; jj < 4; ++jj) {
                        o0[jj] = fmaf(s0[jj], inv, q0[jj]);
                        o1[jj] = fmaf(s1[jj], inv, q1[jj]);
                        v[jj] = f2b(o0[jj]); v[4 + jj] = f2b(o1[jj]);
                    }
                    float* op = &outq[(size_t)row * 128 + k0];
                    *(f32x4*)&op[0] = o0;
                    *(f32x4*)&op[4] = o1;
                } else {
                    int k0 = (kb - 4) * 32 + ch * 8;
                    const short* b = &s_mc[(i * 3) * 256 + k0];
                    short8 m0 = *(const short8*)&b[0];
                    short8 m1 = *(const short8*)&b[256];
                    short8 m2 = *(const short8*)&b[512];
#pragma unroll
                    for (int jj = 0; jj < 8; ++jj) {
                        float a0 = b2f(m0[jj]), a1 = b2f(m1[jj]), a2 = b2f(m2[jj]);
                        v[jj] = f2b(sqrtf(fmaf(a0, a0, fmaf(a1, a1, fmaf(a2, a2, 1e-8f)))));
                    }
                }
            }
            *(short8*)&As[i * 32 + ((ch ^ (i & 3)) * 8)] = v;
        }
        __syncthreads();
        short8 a[2];
#pragma unroll
        for (int rt = 0; rt < 2; ++rt) {
            int row = rt * 16 + lr;
            a[rt] = *(const short8*)&As[row * 32 + ((lg ^ (row & 3)) * 8)];
        }
#pragma unroll
        for (int j = 0; j < 6; ++j) {
            int ct = w * 6 + j;
            short8 B = *(const short8*)&pwA[((size_t)(kb * 24 + ct) * 64 + l) * 8];
#pragma unroll
            for (int rt = 0; rt < 2; ++rt)
                acc1[rt][j] = __builtin_amdgcn_mfma_f32_16x16x32_bf16(a[rt], B, acc1[rt][j], 0, 0, 0);
        }
        __syncthreads();
    }
#pragma unroll
    for (int j = 0; j < 6; ++j) {
        int colL = (w * 6 + j) * 16 + lr;
        float bv = biasA[colL];
        int cb = colL >> 3, pos = colL & 7;
#pragma unroll
        for (int rt = 0; rt < 2; ++rt)
#pragma unroll
            for (int reg = 0; reg < 4; ++reg) {
                int rowg = rt * 16 + lg * 4 + reg;
                s_hh[rowg * 384 + ((cb ^ (rowg & 7)) * 8) + pos] = f2b(silu_f(acc1[rt][j][reg] + bv));
            }
    }
    __syncthreads();

    // ---- phase B: layer 2 ----
    f32x4 acc2[2][6];
#pragma unroll
    for (int rt = 0; rt < 2; ++rt)
#pragma unroll
        for (int j = 0; j < 6; ++j) acc2[rt][j] = (f32x4){0.f, 0.f, 0.f, 0.f};
#pragma unroll
    for (int kb2 = 0; kb2 < 12; ++kb2) {
        short8 a2[2];
#pragma unroll
        for (int rt = 0; rt < 2; ++rt) {
            int row = rt * 16 + lr;
            a2[rt] = *(const short8*)&s_hh[row * 384 + (((kb2 * 4 + lg) ^ (row & 7)) * 8)];
        }
#pragma unroll
        for (int j = 0; j < 6; ++j) {
            int ct = w * 6 + j;
            short8 B = *(const short8*)&pwB[((size_t)(kb2 * 24 + ct) * 64 + l) * 8];
#pragma unroll
            for (int rt = 0; rt < 2; ++rt)
                acc2[rt][j] = __builtin_amdgcn_mfma_f32_16x16x32_bf16(a2[rt], B, acc2[rt][j], 0, 0, 0);
        }
    }
    __syncthreads();

    // delta (bf16) -> s_hh, row-major [32][384]
#pragma unroll
    for (int j = 0; j < 6; ++j) {
        int colL = (w * 6 + j) * 16 + lr;
        float bv = biasB[colL];
#pragma unroll
        for (int rt = 0; rt < 2; ++rt)
#pragma unroll
            for (int reg = 0; reg < 4; ++reg) {
                int rowg = rt * 16 + lg * 4 + reg;
                s_hh[rowg * 384 + colL] = f2b(acc2[rt][j][reg] + bv);
            }
    }
    __syncthreads();

    // ---- final: outq += dq + dqmu*inner ; outmu += mu_w * dmu_scale ----
    {
        int nl = t >> 3;
        int k0 = (t & 7) * 16;
        int n = n0 + nl;
        if (n < N) {
#pragma unroll
            for (int half = 0; half < 2; ++half) {
                int k = k0 + half * 8;
                short8 dq8 = *(const short8*)&s_hh[nl * 384 + k];
                short8 ds8 = *(const short8*)&s_hh[nl * 384 + 128 + k];
                short8 dm8 = *(const short8*)&s_hh[nl * 384 + 256 + k];
                float inner[8] = {0.f, 0.f, 0.f, 0.f, 0.f, 0.f, 0.f, 0.f};
                float mwv[3][8];
#pragma unroll
                for (int c = 0; c < 3; ++c) {
                    const short* mc = &s_mc[(nl * 3 + c) * 256 + k];
                    short8 v8 = *(const short8*)&mc[0];
                    short8 w8 = *(const short8*)&mc[128];
#pragma unroll
                    for (int jj = 0; jj < 8; ++jj) {
                        float mw = b2f(w8[jj]);
                        inner[jj] = fmaf(b2f(v8[jj]), mw, inner[jj]);
                        mwv[c][jj] = mw;
                    }
                }
                float* qp2 = &outq[(size_t)n * 128 + k];
                f32x4 u0 = *(const f32x4*)&qp2[0];
                f32x4 u1 = *(const f32x4*)&qp2[4];
#pragma unroll
                for (int jj = 0; jj < 4; ++jj) {
                    u0[jj] += b2f(dq8[jj]) + b2f(dm8[jj]) * inner[jj];
                    u1[jj] += b2f(dq8[4 + jj]) + b2f(dm8[4 + jj]) * inner[4 + jj];
                }
                *(f32x4*)&qp2[0] = u0;
                *(f32x4*)&qp2[4] = u1;
#pragma unroll
                for (int c = 0; c < 3; ++c) {
                    float* mp = &outmu[((size_t)n * 3 + c) * 128 + k];
                    f32x4 a0 = *(const f32x4*)&mp[0];
                    f32x4 a1 = *(const f32x4*)&mp[4];
#pragma unroll
                    for (int jj = 0; jj < 4; ++jj) {
                        a0[jj] = fmaf(mwv[c][jj], b2f(ds8[jj]), a0[jj]);
                        a1[jj] = fmaf(mwv[c][4 + jj], b2f(ds8[4 + jj]), a1[jj]);
                    }
                    *(f32x4*)&mp[0] = a0;
                    *(f32x4*)&mp[4] = a1;
                }
            }
        }
    }
}

// ---------------------------------------------------------------------------
// Counting sort prefix scan (histogram lives in prep)
// ---------------------------------------------------------------------------
__global__ __launch_bounds__(1024) void scan_kernel(const int* __restrict__ deg_i,
                                                    int* __restrict__ offs, int N) {
    __shared__ int s[1024];
    int t = threadIdx.x;
    int chunk = (N + 1023) / 1024;
    int a = t * chunk, b = min(a + chunk, N);
    int sum = 0;
    for (int i = a; i < b; ++i) sum += deg_i[i];
    s[t] = sum;
    __syncthreads();
    for (int d = 1; d < 1024; d <<= 1) {
        int v = (t >= d) ? s[t - d] : 0;
        __syncthreads();
        s[t] += v;
        __syncthreads();
    }
    int run = (t > 0) ? s[t - 1] : 0;
    for (int i = a; i < b; ++i) { offs[i] = run; run += deg_i[i]; }
}

// ---------------------------------------------------------------------------
// Segmented scan of the TRANSPOSED bf16 plane [col][row] down sorted targets.
// ---------------------------------------------------------------------------
__device__ __forceinline__ void scan_T(const short* __restrict__ s_pt,
                                       const int* __restrict__ s_tgt,
                                       unsigned bm32, float* __restrict__ dst,
                                       int rowstride, int coloff, int t)
{
    int col = t & 127;
    int r0 = (t >> 7) * 32;
    const short* cp = &s_pt[col * PT + r0];
    float acc = 0.f;
    bool first = (bm32 & 1u) ? false : true;
#pragma unroll
    for (int g = 0; g < 4; ++g) {
        short8 v = *(const short8*)&cp[g * 8];
#pragma unroll
        for (int kk = 0; kk < 8; ++kk) {
            const int k = g * 8 + kk;
            if (k > 0 && ((bm32 >> k) & 1u)) {
                int tg = s_tgt[r0 + k - 1];
                if (tg >= 0) {
                    float* d = dst + (size_t)tg * rowstride + coloff + col;
                    if (first) atomicAdd(d, acc); else *d = acc;
                }
                acc = 0.f; first = false;
            }
            acc += b2f(v[kk]);
        }
    }
    int tg = s_tgt[r0 + 31];
    if (tg >= 0) atomicAdd(dst + (size_t)tg * rowstride + coloff + col, acc);
}

// ---------------------------------------------------------------------------
// Fused edge kernel (MFMA) over target-sorted edges; transposed bf16 plane.
// (round-13 version: separate mfma_plane per plane, short register lifetimes)
// ---------------------------------------------------------------------------
__global__ __launch_bounds__(256, 4) void edge_kernel(
    const int* __restrict__ ei, const int* __restrict__ perm,
    const float* __restrict__ rbf,
    const float* __restrict__ uv, const float* __restrict__ cutv,
    const short* __restrict__ pw1, const short* __restrict__ pw2,
    const float* __restrict__ bf1, const float* __restrict__ bf2,
    const short* __restrict__ x, const short* __restrict__ mu_b,
    float* __restrict__ scalar_msg, float* __restrict__ vector_msg,
    int E)
{
    __shared__ __align__(16) short s_h[64 * 128];
    __shared__ __align__(16) short s_pt[128 * PT];
    __shared__ int   s_eid[TE];
    __shared__ int   s_tgt[TE];
    __shared__ int   s_src[TE];
    __shared__ float s_cut[TE];
    __shared__ float s_uv[TE * 3];

    const int t = threadIdx.x;
    const int w = t >> 6;
    const int l = t & 63;
    const int e0 = blockIdx.x * TE;

    if (t < TE) {
        int p = e0 + t;
        int e = (p < E) ? perm[p] : -1;
        s_eid[t] = e;
        s_tgt[t] = (e >= 0) ? ei[e] : -1;
        s_src[t] = (e >= 0) ? ei[(size_t)E + e] : 0;
        s_cut[t] = (e >= 0) ? cutv[e] : 0.f;
    }
    __syncthreads();
    if (t < TE * 3) {
        int i = t / 3, c = t - i * 3;
        int e = s_eid[i];
        s_uv[t] = (e >= 0) ? uv[(size_t)e * 3 + c] : 0.f;
    }
    bool bp = (l > 0) && (s_tgt[l] != s_tgt[l - 1]);
    unsigned long long bl = __ballot(bp);
    unsigned bmlo = __builtin_amdgcn_readfirstlane((unsigned)bl);
    unsigned bmhi = __builtin_amdgcn_readfirstlane((unsigned)(bl >> 32));

    // ---- MFMA1: h = silu(rbf @ Wf1 + bf1) ----
    short8 Ar;
#pragma unroll
    for (int j = 0; j < 8; ++j) Ar[j] = 0;
    {
        int erow = w * 16 + (l & 15);
        int eidr = s_eid[erow];
        int g = l >> 4;
        if (eidr >= 0) {
            const float* rp = &rbf[(size_t)eidr * RDIM];
            if (g < 2) {
                float4 f0 = *(const float4*)&rp[g * 8];
                float4 f1 = *(const float4*)&rp[g * 8 + 4];
                Ar[0] = f2b(f0.x); Ar[1] = f2b(f0.y); Ar[2] = f2b(f0.z); Ar[3] = f2b(f0.w);
                Ar[4] = f2b(f1.x); Ar[5] = f2b(f1.y); Ar[6] = f2b(f1.z); Ar[7] = f2b(f1.w);
            } else if (g == 2) {
                float4 f0 = *(const float4*)&rp[16];
                Ar[0] = f2b(f0.x); Ar[1] = f2b(f0.y); Ar[2] = f2b(f0.z); Ar[3] = f2b(f0.w);
            }
        }
    }
    {
        f32x4 Hc[8];
#pragma unroll
        for (int ct = 0; ct < 8; ++ct) {
            f32x4 z = {0.f, 0.f, 0.f, 0.f};
            short8 Bw = *(const short8*)&pw1[(ct * 64 + l) * 8];
            Hc[ct] = __builtin_amdgcn_mfma_f32_16x16x32_bf16(Ar, Bw, z, 0, 0, 0);
        }
#pragma unroll
        for (int ct = 0; ct < 8; ++ct) {
            int colbase = ct * 16 + (l & 15);
            float b1 = bf1[colbase];
#pragma unroll
            for (int reg = 0; reg < 4; ++reg) {
                int rowg = w * 16 + ((l >> 4) * 4 + reg);
                float v = silu_f(Hc[ct][reg] + b1);
                s_h[rowg * 128 + (((colbase >> 3) ^ (rowg & 7)) * 8) + (colbase & 7)] = f2b(v);
            }
        }
    }
    __syncthreads();

    const int tj = t & 15, ti = t >> 4;
    const int c0 = tj * 8;
    const int r0d = 4 * ((ti + tj) & 15);

    auto mfma_plane = [&](int p) {
        f32x4 C[4][2];
#pragma unroll
        for (int rt = 0; rt < 4; ++rt)
#pragma unroll
            for (int c2 = 0; c2 < 2; ++c2) C[rt][c2] = (f32x4){0.f, 0.f, 0.f, 0.f};
#pragma unroll
        for (int kb = 0; kb < 4; ++kb) {
            short8 A[4];
#pragma unroll
            for (int rt = 0; rt < 4; ++rt) {
                int row = rt * 16 + (l & 15);
                A[rt] = *(const short8*)&s_h[row * 128 + (((kb * 4 + (l >> 4)) ^ (row & 7)) * 8)];
            }
#pragma unroll
            for (int c2 = 0; c2 < 2; ++c2) {
                int ct = p * 8 + w * 2 + c2;
                short8 B = *(const short8*)&pw2[(((kb * 24 + ct) * 64 + l) * 8)];
#pragma unroll
                for (int rt = 0; rt < 4; ++rt)
                    C[rt][c2] = __builtin_amdgcn_mfma_f32_16x16x32_bf16(A[rt], B, C[rt][c2], 0, 0, 0);
            }
        }
        const int lg = l >> 4;
#pragma unroll
        for (int c2 = 0; c2 < 2; ++c2) {
            int colL = w * 32 + c2 * 16 + (l & 15);
            float bv = bf2[p * 128 + colL];
#pragma unroll
            for (int rt = 0; rt < 4; ++rt) {
                float4 cu4 = *(float4*)&s_cut[rt * 16 + lg * 4];
                float v0 = (C[rt][c2][0] + bv) * cu4.x;
                float v1 = (C[rt][c2][1] + bv) * cu4.y;
                float v2 = (C[rt][c2][2] + bv) * cu4.z;
                float v3 = (C[rt][c2][3] + bv) * cu4.w;
                *(uint2*)&s_pt[colL * PT + rt * 16 + lg * 4] =
                    make_uint2(cvt_pk_bf16(v0, v1), cvt_pk_bf16(v2, v3));
            }
        }
    };

    // plane 0: filter_q -> scalar messages
    mfma_plane(0);
    __syncthreads();
    {
        float xf[4][8];
#pragma unroll
        for (int rr = 0; rr < 4; ++rr) {
            int s = s_src[r0d + rr];
            short8 xv = *(const short8*)&x[(size_t)s * 384 + c0];
#pragma unroll
            for (int c = 0; c < 8; ++c) xf[rr][c] = b2f(xv[c]);
        }
#pragma unroll
        for (int cc = 0; cc < 8; ++cc) {
            short* pp = &s_pt[(c0 + cc) * PT + r0d];
            s16x4 pv = *(s16x4*)pp;
            float o0 = b2f(pv[0]) * xf[0][cc];
            float o1 = b2f(pv[1]) * xf[1][cc];
            float o2 = b2f(pv[2]) * xf[2][cc];
            float o3 = b2f(pv[3]) * xf[3][cc];
            *(uint2*)pp = make_uint2(cvt_pk_bf16(o0, o1), cvt_pk_bf16(o2, o3));
        }
    }
    __syncthreads();
    scan_T(s_pt, s_tgt, (t >> 7) ? bmhi : bmlo, scalar_msg, HDIM, 0, t);
    __syncthreads();

    // plane 1: filter_r -> vr
    mfma_plane(1);
    __syncthreads();
    float vr[4][8];
    {
        float xf[4][8];
#pragma unroll
        for (int rr = 0; rr < 4; ++rr) {
            int s = s_src[r0d + rr];
            short8 xv = *(const short8*)&x[(size_t)s * 384 + 128 + c0];
#pragma unroll
            for (int c = 0; c < 8; ++c) xf[rr][c] = b2f(xv[c]);
        }
#pragma unroll
        for (int cc = 0; cc < 8; ++cc) {
            s16x4 pv = *(const s16x4*)&s_pt[(c0 + cc) * PT + r0d];
#pragma unroll
            for (int rr = 0; rr < 4; ++rr) vr[rr][cc] = b2f(pv[rr]) * xf[rr][cc];
        }
    }
    __syncthreads();

    // plane 2: filter_mu -> vm
    mfma_plane(2);
    __syncthreads();
    float vm[4][8];
    {
        float xf[4][8];
#pragma unroll
        for (int rr = 0; rr < 4; ++rr) {
            int s = s_src[r0d + rr];
            short8 xv = *(const short8*)&x[(size_t)s * 384 + 256 + c0];
#pragma unroll
            for (int c = 0; c < 8; ++c) xf[rr][c] = b2f(xv[c]);
        }
#pragma unroll
        for (int cc = 0; cc < 8; ++cc) {
            s16x4 pv = *(const s16x4*)&s_pt[(c0 + cc) * PT + r0d];
#pragma unroll
            for (int rr = 0; rr < 4; ++rr) vm[rr][cc] = b2f(pv[rr]) * xf[rr][cc];
        }
    }

    // vector components x/y/z: combine + scan
#pragma unroll
    for (int comp = 0; comp < 3; ++comp) {
        if (comp > 0) __syncthreads();
        float uvv[4], mf[4][8];
#pragma unroll
        for (int rr = 0; rr < 4; ++rr) {
            uvv[rr] = s_uv[(r0d + rr) * 3 + comp];
            int s = s_src[r0d + rr];
            short8 mv = *(const short8*)&mu_b[(size_t)s * 384 + comp * 128 + c0];
#pragma unroll
            for (int c = 0; c < 8; ++c) mf[rr][c] = b2f(mv[c]);
        }
#pragma unroll
        for (int cc = 0; cc < 8; ++cc) {
            float o0 = fmaf(uvv[0], vr[0][cc], mf[0][cc] * vm[0][cc]);
            float o1 = fmaf(uvv[1], vr[1][cc], mf[1][cc] * vm[1][cc]);
            float o2 = fmaf(uvv[2], vr[2][cc], mf[2][cc] * vm[2][cc]);
            float o3 = fmaf(uvv[3], vr[3][cc], mf[3][cc] * vm[3][cc]);
            *(uint2*)&s_pt[(c0 + cc) * PT + r0d] =
                make_uint2(cvt_pk_bf16(o0, o1), cvt_pk_bf16(o2, o3));
        }
        __syncthreads();
        scan_T(s_pt, s_tgt, (t >> 7) ? bmhi : bmlo, vector_msg, 384, comp * 128, t);
    }
}

// ---------------------------------------------------------------------------
extern "C" void kernel_launch(void* const* d_in, const int* in_sizes, int n_in,
                              void* d_out, int out_size, void* d_ws, size_t ws_size,
                              hipStream_t stream)
{
    const float* q    = (const float*)d_in[0];
    const float* mu   = (const float*)d_in[1];
    const int*   ei   = (const int*)d_in[2];
    const float* rbf  = (const float*)d_in[3];
    const float* uv   = (const float*)d_in[4];
    const float* cutv = (const float*)d_in[5];
    const float* Wi1  = (const float*)d_in[6];
    const float* bi1  = (const float*)d_in[7];
    const float* Wi2  = (const float*)d_in[8];
    const float* bi2  = (const float*)d_in[9];
    const float* Wf1  = (const float*)d_in[10];
    const float* bf1  = (const float*)d_in[11];
    const float* Wf2  = (const float*)d_in[12];
    const float* bf2  = (const float*)d_in[13];
    const float* Wv   = (const float*)d_in[14];
    const float* Ws1  = (const float*)d_in[15];
    const float* bs1  = (const float*)d_in[16];
    const float* Ws2  = (const float*)d_in[17];
    const float* bs2  = (const float*)d_in[18];

    const int N = in_sizes[0] / HDIM;     // 10000
    const int E = in_sizes[2] / 2;        // 320000

    float* ws = (float*)d_ws;
    float* scalar_msg = ws;
    float* vector_msg = ws + (size_t)N * 128;
    short* xbuf       = (short*)(ws + (size_t)N * 512);
    short* mu_b       = (short*)(ws + (size_t)N * 704);
    int*   ibase      = (int*)(ws + (size_t)N * 896);
    int*   deg_i      = ibase;
    int*   counters   = ibase + N;
    int*   offs       = ibase + 2 * (size_t)N;
    int*   perm       = ibase + 3 * (size_t)N;
    short* pk         = (short*)(perm + E);

    float* outq  = (float*)d_out;
    float* outmu = (float*)d_out + (size_t)N * 128;

    hipMemsetAsync(ibase, 0, (size_t)2 * N * sizeof(int), stream);    // deg + counters

    dim3 blk(256);
    int prep_items = PK_TOTAL + N * 48 + E + N * 128;
    prep_kernel<<<(prep_items + 255) / 256, blk, 0, stream>>>(Wf1, Wf2, Wi1, Wi2, Wv, Ws1, Ws2,
                                                              pk, mu, mu_b, ei, deg_i,
                                                              scalar_msg, N, E);

    scan_kernel<<<1, dim3(1024), 0, stream>>>(deg_i, offs, N);

    int MB = (N + 31) / 32;
    int SB = (E + 255) / 256;
    mlp1_scatter_kernel<<<MB + SB, blk, 0, stream>>>(q, pk + OFF_PWI1, bi1,
                                                     pk + OFF_PWI2, bi2, xbuf, N, MB,
                                                     ei, offs, counters, perm, E);

    edge_kernel<<<(E + TE - 1) / TE, blk, 0, stream>>>(ei, perm, rbf, uv, cutv,
                                                       pk + OFF_PW1, pk + OFF_PW2, bf1, bf2,
                                                       xbuf, mu_b, scalar_msg, vector_msg, E);

    mix_kernel<<<(N + 31) / 32, blk, 0, stream>>>(mu, vector_msg, q, scalar_msg, deg_i,
                                                  pk + OFF_PWV, pk + OFF_PWS1, bs1,
                                                  pk + OFF_PWS2, bs2, outq, outmu, N);
}